// Round 5
// baseline (192.003 us; speedup 1.0000x reference)
//
#include <hip/hip_runtime.h>
#include <cstddef>

#define CC 256
#define HH 128
#define WW 128
#define HW (HH*WW)          // 16384

typedef __attribute__((ext_vector_type(8))) short short8v;   // 8 bf16
typedef __attribute__((ext_vector_type(4))) float float4v;   // MFMA acc

__device__ __forceinline__ short f2bf(float x) {
    unsigned u = __float_as_uint(x);
    u += 0x7FFFu + ((u >> 16) & 1u);      // RNE to bf16
    return (short)(u >> 16);
}

// async global->LDS, 16B per lane: LDS dest = uniform base + lane*16,
// global src = per-lane address.
__device__ __forceinline__ void gload16(const float* g, float* l) {
    __builtin_amdgcn_global_load_lds(
        (const __attribute__((address_space(1))) void*)g,
        (__attribute__((address_space(3))) void*)l, 16, 0, 0);
}

#define WAITVM(N) { asm volatile("s_waitcnt vmcnt(" #N ")" ::: "memory"); \
                    __builtin_amdgcn_sched_barrier(0); }
#define WAITLGKM  { asm volatile("s_waitcnt lgkmcnt(0)" ::: "memory"); \
                    __builtin_amdgcn_sched_barrier(0); }

// pool keys from staged fp32 half (wave-private rows v*8..v*8+7)
__device__ __forceinline__ void pool_keys(
    const float* S, short* kH, short* kWT, int v, int l, int half)
{
    // H-pool: lane owns cols l and l+64
    float sA = 0.f, sB = 0.f;
    #pragma unroll
    for (int j = 0; j < 8; ++j) {
        sA += S[(v*8+j)*128 + l];
        sB += S[(v*8+j)*128 + 64 + l];
    }
    const int k = half*8 + v;
    const int s = (k & 7) << 3;
    kH[k*128 + (l ^ s)]        = f2bf(sA * 0.125f);
    kH[k*128 + ((l+64) ^ s)]   = f2bf(sB * 0.125f);
    // W-pool: lane owns row (l>>3), kw pair 2*(l&7), 2*(l&7)+1
    const int row = v*8 + (l >> 3);
    const float4* Sr = (const float4*)&S[row*128];
    float4 a0 = Sr[(l&7)*4+0], a1 = Sr[(l&7)*4+1];
    float4 a2 = Sr[(l&7)*4+2], a3 = Sr[(l&7)*4+3];
    const int h  = half*64 + row;
    const int kw = (l & 7) * 2;
    kWT[kw*128     + (h ^ ((kw&7)<<3))]     =
        f2bf((a0.x+a0.y+a0.z+a0.w + a1.x+a1.y+a1.z+a1.w) * 0.125f);
    kWT[(kw+1)*128 + (h ^ (((kw+1)&7)<<3))] =
        f2bf((a2.x+a2.y+a2.z+a2.w + a3.x+a3.y+a3.z+a3.w) * 0.125f);
}

// t2 half: pools -> global valH/valW, bf16 tiles t2lds/t2T
__device__ __forceinline__ void process_t2(
    const float* S, short* t2lds, short* t2T,
    float* valH, float* valW, int bc, int v, int l, int half)
{
    // columns l and l+64: valH sums + t2T columns in one pass
    float sA = 0.f, sB = 0.f;
    short8v colA, colB;
    #pragma unroll
    for (int j = 0; j < 8; ++j) {
        float xa = S[(v*8+j)*128 + l];
        float xb = S[(v*8+j)*128 + 64 + l];
        sA += xa; sB += xb;
        colA[j] = f2bf(xa); colB[j] = f2bf(xb);
    }
    {
        const int wA = l, wB = l + 64;
        *(short8v*)&t2T[wA*64 + ((v*8) ^ ((wA&7)<<3))] = colA;
        *(short8v*)&t2T[wB*64 + ((v*8) ^ ((wB&7)<<3))] = colB;
    }
    {
        const int k = half*8 + v;
        const size_t vb = ((size_t)bc*16 + k)*128;
        valH[vb + l]      = sA * 0.125f;
        valH[vb + 64 + l] = sB * 0.125f;
    }
    // valW: lane owns row (l>>3), kw pair
    {
        const int row = v*8 + (l >> 3);
        const float4* Sr = (const float4*)&S[row*128];
        float4 a0 = Sr[(l&7)*4+0], a1 = Sr[(l&7)*4+1];
        float4 a2 = Sr[(l&7)*4+2], a3 = Sr[(l&7)*4+3];
        const int h = half*64 + row;
        float2 vw;
        vw.x = (a0.x+a0.y+a0.z+a0.w + a1.x+a1.y+a1.z+a1.w) * 0.125f;
        vw.y = (a2.x+a2.y+a2.z+a2.w + a3.x+a3.y+a3.z+a3.w) * 0.125f;
        *(float2*)&valW[(size_t)bc*2048 + (size_t)h*16 + (l&7)*2] = vw;
    }
    // t2lds row-major tile (4 b128 tasks)
    #pragma unroll
    for (int t = 0; t < 4; ++t) {
        const int j = t*2 + (l>>5);
        const int q = l & 31;
        float4 x = ((const float4*)&S[(v*8+j)*128])[q];
        short4 p; p.x=f2bf(x.x); p.y=f2bf(x.y); p.z=f2bf(x.z); p.w=f2bf(x.w);
        const int hl = v*8 + j;
        *(short4*)&t2lds[hl*128 + ((q*4) ^ ((hl&7)<<3))] = p;
    }
}

__device__ __forceinline__ float4v mfma16(short8v a, short8v b, float4v c) {
    return __builtin_amdgcn_mfma_f32_16x16x32_bf16(a, b, c, 0, 0, 0);
}

// MFMA for one half: waves 0-3 -> H tiles, waves 4-7 -> W tiles
__device__ __forceinline__ void mfma_half(
    const short* t2lds, const short* t2T, const short* kH, const short* kWT,
    int v, int l, int half, float4v& accH, float4v& accW0, float4v& accW1)
{
    if (v < 4) {
        const int hl = v*16 + (l & 15);
        const int kb = l & 15;
        const int sA = (hl & 7) << 3, sB = (kb & 7) << 3;
        #pragma unroll
        for (int ws2 = 0; ws2 < 4; ++ws2) {
            const int wb = ws2*32 + (l>>4)*8;
            short8v A = *(const short8v*)&t2lds[hl*128 + (wb ^ sA)];
            short8v B = *(const short8v*)&kH  [kb*128 + (wb ^ sB)];
            accH = mfma16(A, B, accH);
        }
    } else {
        const int kb  = l & 15;
        const int skb = (kb & 7) << 3;
        #pragma unroll
        for (int wt2 = 0; wt2 < 2; ++wt2) {
            const int w  = ((v-4)*2 + wt2)*16 + (l & 15);
            const int sw = (w & 7) << 3;
            #pragma unroll
            for (int hs = 0; hs < 2; ++hs) {
                const int hloc = hs*32 + (l>>4)*8;
                const int hg   = half*64 + hloc;
                short8v A = *(const short8v*)&kWT[kb*128 + (hg ^ skb)];
                short8v B = *(const short8v*)&t2T[w*64   + (hloc ^ sw)];
                if (wt2 == 0) accW0 = mfma16(A, B, accW0);
                else          accW1 = mfma16(A, B, accW1);
            }
        }
    }
}

// ============ Kernel 1: fused pooling + both energies ============
// grid 2048 (b = bid&7, c = bid>>3), block 512 (8 waves).
// Wave v owns rows v*8..v*8+7 of each 64-row half: staging is wave-private.
__global__ __launch_bounds__(512) void fused_pool_energy(
    const float* __restrict__ t1, const float* __restrict__ t2,
    float* __restrict__ valH, float* __restrict__ valW,
    float* __restrict__ PH, float* __restrict__ PW)
{
    __shared__ __align__(16) float S0[64*128];     // 32 KB  t1h0 -> t2h1
    __shared__ __align__(16) float S1[64*128];     // 32 KB  t1h1
    __shared__ __align__(16) float S2[64*128];     // 32 KB  t2h0
    __shared__ __align__(16) short t2lds[64*128];  // 16 KB
    __shared__ __align__(16) short t2T[128*64];    // 16 KB
    __shared__ __align__(16) short kH [16*128];    //  4 KB
    __shared__ __align__(16) short kWT[16*128];    //  4 KB

    const int bid = blockIdx.x;
    const int b = bid & 7, c = bid >> 3;
    const int tid = threadIdx.x;
    const int l = tid & 63;
    const int v = tid >> 6;
    const int bc = b*CC + c;
    const float* t1c = t1 + (size_t)bc * HW;
    const float* t2c = t2 + (size_t)bc * HW;
    const int r0 = v * 8;

    // ---- issue all staging upfront: t1h0(4), t1h1(4), t2h0(4) ----
    #pragma unroll
    for (int i = 0; i < 4; ++i)
        gload16(t1c + (size_t)(r0 + 2*i)*WW + l*4, &S0[(r0 + 2*i)*128]);
    __builtin_amdgcn_sched_barrier(0);
    #pragma unroll
    for (int i = 0; i < 4; ++i)
        gload16(t1c + (size_t)(64 + r0 + 2*i)*WW + l*4, &S1[(r0 + 2*i)*128]);
    __builtin_amdgcn_sched_barrier(0);
    #pragma unroll
    for (int i = 0; i < 4; ++i)
        gload16(t2c + (size_t)(r0 + 2*i)*WW + l*4, &S2[(r0 + 2*i)*128]);
    __builtin_amdgcn_sched_barrier(0);

    float4v accH0 = {0.f,0.f,0.f,0.f}, accH1 = {0.f,0.f,0.f,0.f};
    float4v accW0 = {0.f,0.f,0.f,0.f}, accW1 = {0.f,0.f,0.f,0.f};

    // ---- keys ----
    WAITVM(8);                       // t1h0 landed (own wave's calls)
    pool_keys(S0, kH, kWT, v, l, 0);
    WAITVM(4);                       // t1h1 landed
    pool_keys(S1, kH, kWT, v, l, 1);

    // reuse S0 for t2h1 (wave-private rows; own reads must retire first)
    WAITLGKM;
    #pragma unroll
    for (int i = 0; i < 4; ++i)
        gload16(t2c + (size_t)(64 + r0 + 2*i)*WW + l*4, &S0[(r0 + 2*i)*128]);
    __builtin_amdgcn_sched_barrier(0);

    // ---- half 0 ----
    WAITVM(4);                       // t2h0 landed (t2h1 still flying)
    process_t2(S2, t2lds, t2T, valH, valW, bc, v, l, 0);
    WAITLGKM;                        // tile writes visible
    __builtin_amdgcn_s_barrier();
    mfma_half(t2lds, t2T, kH, kWT, v, l, 0, accH0, accW0, accW1);
    WAITLGKM;                        // my fragment reads retired
    __builtin_amdgcn_s_barrier();    // everyone done reading tiles

    // ---- half 1 ----
    WAITVM(0);
    process_t2(S0, t2lds, t2T, valH, valW, bc, v, l, 1);
    WAITLGKM;
    __builtin_amdgcn_s_barrier();
    mfma_half(t2lds, t2T, kH, kWT, v, l, 1, accH1, accW0, accW1);

    // ---- write partials ----
    const size_t pb = (size_t)bc * 2048;
    if (v < 4) {
        #pragma unroll
        for (int r = 0; r < 4; ++r) {
            const int row = (l>>4)*4 + r;
            PH[pb + (size_t)(v*16 + row)*16 + (l&15)]       = accH0[r];
            PH[pb + (size_t)((v+4)*16 + row)*16 + (l&15)]   = accH1[r];
        }
    } else {
        #pragma unroll
        for (int r = 0; r < 4; ++r) {
            const int k = (l>>4)*4 + r;
            PW[pb + (size_t)k*128 + ((v-4)*2+0)*16 + (l&15)] = accW0[r];
            PW[pb + (size_t)k*128 + ((v-4)*2+1)*16 + (l&15)] = accW1[r];
        }
    }
}

// ============ Kernel 2: reduce partials (256 chunks) -> energy[8][4096] ============
__global__ __launch_bounds__(256) void energy_reduce(
    const float* __restrict__ PH, const float* __restrict__ PW,
    float* __restrict__ energy, float* __restrict__ bmin, float* __restrict__ bmax)
{
    const int bidx = blockIdx.x;           // 0..511
    const int tid  = threadIdx.x;
    const int ol   = tid & 63, qd = tid >> 6;
    const int o    = bidx*64 + ol;         // 0..32767
    __shared__ float red[4][64];

    const int isW = o >> 14;
    const int oo  = o & 16383;
    const int b   = oo >> 11, i = oo & 2047;
    const float* P = (isW ? PW : PH) + (size_t)b*256*2048 + i;
    float s = 0.f;
    #pragma unroll 8
    for (int j = 0; j < 64; ++j) s += P[(size_t)(qd*64 + j)*2048];
    red[qd][ol] = s;
    __syncthreads();

    if (tid < 64) {
        float v = red[0][tid] + red[1][tid] + red[2][tid] + red[3][tid];
        const int o2 = bidx*64 + tid;
        const int oo2 = o2 & 16383;
        const int b2 = oo2 >> 11, i2 = oo2 & 2047;
        const size_t dst = (o2 >> 14)
            ? ((size_t)b2*4096 + 2048 + (size_t)(i2 & 127)*16 + (i2 >> 7))
            : ((size_t)b2*4096 + i2);
        energy[dst] = v;
        float mn = v, mx = v;
        #pragma unroll
        for (int sft = 32; sft > 0; sft >>= 1) {
            mn = fminf(mn, __shfl_xor(mn, sft));
            mx = fmaxf(mx, __shfl_xor(mx, sft));
        }
        if (tid == 0) { bmin[bidx] = mn; bmax[bidx] = mx; }
    }
}

// ============ Kernel 3: softmax (8 blocks, one row each) ============
__global__ __launch_bounds__(1024) void softmax_kernel(
    const float* __restrict__ energy, const float* __restrict__ bmin,
    const float* __restrict__ bmax, float* __restrict__ att)
{
    const int b = blockIdx.x, tid = threadIdx.x;
    const int lane = tid & 63, wid = tid >> 6;     // 16 waves
    __shared__ float smn[16], smx[16], sred[16], bc2[2];

    float mn = 3.0e38f, mx = -3.0e38f;
    if (tid < 512) { mn = bmin[tid]; mx = bmax[tid]; }
    #pragma unroll
    for (int s = 32; s > 0; s >>= 1) {
        mn = fminf(mn, __shfl_xor(mn, s));
        mx = fmaxf(mx, __shfl_xor(mx, s));
    }
    if (lane == 0) { smn[wid] = mn; smx[wid] = mx; }
    __syncthreads();
    if (tid == 0) {
        float a = smn[0], m = smx[0];
        #pragma unroll
        for (int i = 1; i < 16; ++i) { a = fminf(a, smn[i]); m = fmaxf(m, smx[i]); }
        bc2[0] = a; bc2[1] = m;
    }
    __syncthreads();
    const float gmn = bc2[0];
    const float inv = 1.0f / (bc2[1] - gmn);

    float4 v = ((const float4*)energy)[b*1024 + tid];
    float4 e;
    e.x = __expf((v.x - gmn) * inv);
    e.y = __expf((v.y - gmn) * inv);
    e.z = __expf((v.z - gmn) * inv);
    e.w = __expf((v.w - gmn) * inv);
    float loc = e.x + e.y + e.z + e.w;
    #pragma unroll
    for (int s = 32; s > 0; s >>= 1) loc += __shfl_down(loc, s);
    if (lane == 0) sred[wid] = loc;
    __syncthreads();
    if (tid == 0) {
        float a = 0.f;
        #pragma unroll
        for (int j = 0; j < 16; ++j) a += sred[j];
        bc2[0] = 1.0f / a;
    }
    __syncthreads();
    const float r = bc2[0];
    e.x *= r; e.y *= r; e.z *= r; e.w *= r;
    ((float4*)att)[b*1024 + tid] = e;
}

// ============ Kernel 4: recombination ============
// grid 8192 = (b = bid&7, hg = (bid>>3)&3, c = bid>>5), block 128 (w).
__global__ __launch_bounds__(128) void out_kernel(
    const float* __restrict__ t2,
    const float* __restrict__ valH, const float* __restrict__ valW,
    const float* __restrict__ att, float* __restrict__ out)
{
    const int bid = blockIdx.x;
    const int b  = bid & 7;
    const int hg = (bid >> 3) & 3;
    const int c  = bid >> 5;
    const int w  = threadIdx.x;
    const size_t pb = ((size_t)b * CC + c) * 2048;
    const float* vH = valH + pb;                        // [k][w]
    const float* vW = valW + pb;                        // [h][k]
    const float* aH = att + (size_t)b * 4096;           // [h][16]
    const float* aW = att + (size_t)b * 4096 + 2048;    // [w][16]
    const size_t tb = ((size_t)b * CC + c) * HW;

    float vHr[16];
    #pragma unroll
    for (int k = 0; k < 16; ++k) vHr[k] = vH[k * WW + w];

    float aWr[16];
    {
        const float4* p = (const float4*)(aW + w * 16);
        float4 q0 = p[0], q1 = p[1], q2 = p[2], q3 = p[3];
        aWr[0]=q0.x; aWr[1]=q0.y; aWr[2]=q0.z; aWr[3]=q0.w;
        aWr[4]=q1.x; aWr[5]=q1.y; aWr[6]=q1.z; aWr[7]=q1.w;
        aWr[8]=q2.x; aWr[9]=q2.y; aWr[10]=q2.z; aWr[11]=q2.w;
        aWr[12]=q3.x; aWr[13]=q3.y; aWr[14]=q3.z; aWr[15]=q3.w;
    }

    const int hbase = hg * 32;
    #pragma unroll 2
    for (int i = 0; i < 32; ++i) {
        const int h = hbase + i;
        const float tv = t2[tb + (size_t)h * WW + w];
        const float* ah = aH + h * 16;      // wave-uniform, contiguous 64B
        const float* vw = vW + h * 16;      // wave-uniform, contiguous 64B
        float accH = 0.f, accW = 0.f;
        #pragma unroll
        for (int k = 0; k < 16; ++k) {
            accH = fmaf(vHr[k], ah[k], accH);
            accW = fmaf(aWr[k], vw[k], accW);
        }
        out[tb + (size_t)h * WW + w] = 0.5f * (accH + accW) + tv;
    }
}

extern "C" void kernel_launch(void* const* d_in, const int* in_sizes, int n_in,
                              void* d_out, int out_size, void* d_ws, size_t ws_size,
                              hipStream_t stream)
{
    const float* t1 = (const float*)d_in[0];
    const float* t2 = (const float*)d_in[1];
    float* out = (float*)d_out;
    float* ws  = (float*)d_ws;

    float* valH   = ws;                               // 4,194,304 floats
    float* valW   = ws + (size_t)4194304;             // 4,194,304
    float* energy = ws + (size_t)8388608;             //    32,768
    float* att    = ws + (size_t)8421376;             //    32,768
    float* bmin   = ws + (size_t)8454144;             //       512
    float* bmax   = ws + (size_t)8454656;             //       512

    // partials live in d_out (33.5 MB of 134 MB), overwritten by out_kernel
    float* PH = out;                                   // 4,194,304 floats
    float* PW = out + (size_t)4194304;                 // 4,194,304 floats

    hipLaunchKernelGGL(fused_pool_energy, dim3(2048), dim3(512), 0, stream,
                       t1, t2, valH, valW, PH, PW);
    hipLaunchKernelGGL(energy_reduce, dim3(512), dim3(256), 0, stream,
                       PH, PW, energy, bmin, bmax);
    hipLaunchKernelGGL(softmax_kernel, dim3(8), dim3(1024), 0, stream,
                       energy, bmin, bmax, att);
    hipLaunchKernelGGL(out_kernel, dim3(8192), dim3(128), 0, stream,
                       t2, valH, valW, att, out);
}